// Round 5
// baseline (219.032 us; speedup 1.0000x reference)
//
#include <hip/hip_runtime.h>

// MultiHeadAttention B=2,T=2048,D=1024,H=16,hd=64 fp32.
// R13: flash = R12's P-in-registers PV path, restructured:
//  (a) q-tile 128->256: one 512-thread 8-wave block (4 q-quarters x 2
//      key-halves), grid 256 = 1 block/CU. Halves staging + L2 traffic per
//      q-row; per-wave work identical to R12.
//  (b) K/V triple-buffered, stage-AFTER-barrier, counted s_waitcnt vmcnt(2)
//      (2 gl16/wave/tile) -- loads get 2 compute phases; barrier never
//      drains next-tile loads. vmcnt(0) only on the last tile.
//  (c) s_setprio(1) around MFMA clusters.
// LDS 68KB (48KB K/V bufs, 64KB reduce region unioned). gemm_qkv/gemm_out/
// split unchanged from R9/R12.

typedef __attribute__((ext_vector_type(8))) short bf16x8;
typedef __attribute__((ext_vector_type(4))) float f32x4;
typedef __attribute__((ext_vector_type(4))) unsigned int u32x4;
typedef __attribute__((ext_vector_type(2))) unsigned long long u64x2;

#define E22 ((size_t)1 << 22)
#define E20 ((size_t)1 << 20)

__device__ __forceinline__ unsigned short f2bf(float x) {
    unsigned int u = __float_as_uint(x);
    u += 0x7fffu + ((u >> 16) & 1u);
    return (unsigned short)(u >> 16);
}
__device__ __forceinline__ unsigned int pk2bf(float a, float b) {
    // [b_hi16 | a_hi16] in one v_perm_b32
    return __builtin_amdgcn_perm(__float_as_uint(a), __float_as_uint(b), 0x03020706u);
}
__device__ __forceinline__ void gl16(const void* g, void* l) {
    __builtin_amdgcn_global_load_lds(
        (const __attribute__((address_space(1))) void*)g,
        (__attribute__((address_space(3))) void*)l, 16, 0, 0);
}
__device__ __forceinline__ f32x4 mfma16(bf16x8 a, bf16x8 b, f32x4 c) {
    return __builtin_amdgcn_mfma_f32_16x16x32_bf16(a, b, c, 0, 0, 0);
}

// ---------------------------------------------------------------------------
// split: fp32 -> bf16. q/k/v -> [0,3*E22); Wq,Wk,Wv -> Wcat[3072,1024] at
// 3*E22; Wo -> 3*E22+3*E20. 4M threads, one float4 each.
// ---------------------------------------------------------------------------
__global__ __launch_bounds__(256)
void split_all(const float* __restrict__ q, const float* __restrict__ k,
               const float* __restrict__ v, const float* __restrict__ wq,
               const float* __restrict__ wk, const float* __restrict__ wv,
               const float* __restrict__ wo, unsigned short* __restrict__ ws)
{
    const size_t t = (size_t)blockIdx.x * 256 + threadIdx.x;
    const size_t e = t * 4;
    const float* src; unsigned short* dst; size_t off;
    if (e < 3 * E22) {
        const unsigned int which = (unsigned int)(e >> 22);
        src = which == 0 ? q : (which == 1 ? k : v);
        off = e & (E22 - 1);
        dst = ws + (size_t)which * E22;
    } else {
        const size_t e2 = e - 3 * E22;
        const unsigned int which = (unsigned int)(e2 >> 20);
        off = e2 & (E20 - 1);
        src = which == 0 ? wq : (which == 1 ? wk : (which == 2 ? wv : wo));
        dst = ws + 3 * E22 + (size_t)which * E20;
    }
    const float4 xv = *(const float4*)(src + off);
    ushort4 h4;
    h4.x = f2bf(xv.x); h4.y = f2bf(xv.y); h4.z = f2bf(xv.z); h4.w = f2bf(xv.w);
    *(ushort4*)(dst + off) = h4;
}

// ---------------------------------------------------------------------------
// Fused QKV bf16 GEMM. Flat grid 768, XCD swizzle. Q output (which==0) is
// PRE-SCALED by log2e/8 so flash's softmax is a bare exp2.
// R9: 3-buffer LDS, depth-2 prefetch, counted vmcnt(4) + raw s_barrier.
// ---------------------------------------------------------------------------
__global__ __launch_bounds__(256)
void gemm_qkv(const unsigned short* __restrict__ Xall,
              const unsigned short* __restrict__ Wcat,
              const float* __restrict__ bq, const float* __restrict__ bk,
              const float* __restrict__ bv, unsigned short* __restrict__ Qhp,
              unsigned short* __restrict__ Khp, unsigned short* __restrict__ Vtp)
{
    __shared__ unsigned short Xs[3 * 4096], Ws[3 * 4096];   // 3 bufs x 8KB each
    const int tid = threadIdx.x;
    const int w = tid >> 6, ln = tid & 63;
    const int quad = ln >> 4, L = ln & 15;
    const int wy = w >> 1, wx = w & 1;

    const int bid = blockIdx.x;
    const int xcd = bid & 7, j = bid >> 3;
    const int gg = xcd * 12 + (j >> 3);
    const int which = gg >> 5, m_i = gg & 31, n_i = j & 7;
    const int m0 = m_i * 128;

    const unsigned short* X = Xall + (size_t)which * E22;
    const unsigned short* W = Wcat + ((size_t)which * 1024 + n_i * 128) * 1024;
    const float* bp = which == 0 ? bq : (which == 1 ? bk : bv);
    unsigned short* outp = which == 0 ? Qhp : (which == 1 ? Khp : Vtp);
    const float qscale = which == 0 ? 0.18033688011f : 1.0f;   // log2(e)/8

    // staging geometry (loop-invariant): 4 gl16 per wave per K-tile
    const int ci0 = ln, ci1 = 64 + ln;
    const int row0 = w * 32 + (ci0 >> 2), row1 = w * 32 + (ci1 >> 2);
    const int gc0 = (ci0 & 3) ^ ((row0 >> 1) & 3);
    const int gc1 = (ci1 & 3) ^ ((row1 >> 1) & 3);
    const int lb0 = w * 2048, lb1 = w * 2048 + 1024;          // byte offsets
    const unsigned short* Xbp = X + (size_t)m0 * 1024;
    const size_t gx0 = (size_t)row0 * 1024 + gc0 * 8;
    const size_t gx1 = (size_t)row1 * 1024 + gc1 * 8;

    f32x4 acc[4][4];
#pragma unroll
    for (int i = 0; i < 4; ++i)
#pragma unroll
        for (int jj = 0; jj < 4; ++jj) { f32x4 z = {0.f,0.f,0.f,0.f}; acc[i][jj] = z; }

#define QSTAGE(k0_, bo_)                                                       \
    do {                                                                       \
        gl16(Xbp + gx0 + (k0_), (char*)Xs + (bo_) + lb0);                      \
        gl16(W   + gx0 + (k0_), (char*)Ws + (bo_) + lb0);                      \
        gl16(Xbp + gx1 + (k0_), (char*)Xs + (bo_) + lb1);                      \
        gl16(W   + gx1 + (k0_), (char*)Ws + (bo_) + lb1);                      \
    } while (0)

#define QCOMP(eo_)                                                             \
    do {                                                                       \
        const unsigned short* Xc = Xs + (eo_);                                 \
        const unsigned short* Wc = Ws + (eo_);                                 \
        bf16x8 ah[4], bh[4];                                                   \
        _Pragma("unroll")                                                      \
        for (int mt = 0; mt < 4; ++mt) {                                       \
            const int row = wy * 64 + mt * 16 + L;                             \
            ah[mt] = *(const bf16x8*)(Xc + row * 32 +                          \
                                      ((quad ^ ((row >> 1) & 3)) * 8));        \
        }                                                                      \
        _Pragma("unroll")                                                      \
        for (int nt = 0; nt < 4; ++nt) {                                       \
            const int row = wx * 64 + nt * 16 + L;                             \
            bh[nt] = *(const bf16x8*)(Wc + row * 32 +                          \
                                      ((quad ^ ((row >> 1) & 3)) * 8));        \
        }                                                                      \
        _Pragma("unroll")                                                      \
        for (int mt = 0; mt < 4; ++mt)                                         \
            _Pragma("unroll")                                                  \
            for (int nt = 0; nt < 4; ++nt)                                     \
                acc[mt][nt] = mfma16(ah[mt], bh[nt], acc[mt][nt]);             \
    } while (0)

    QSTAGE(0, 0);
    QSTAGE(32, 8192);

    int cur = 0;
    for (int kt = 0; kt < 31; ++kt) {
        // own 4 loads for buf[cur] done; next tile's 4 may stay in flight
        asm volatile("s_waitcnt vmcnt(4)" ::: "memory");
        __builtin_amdgcn_s_barrier();
        asm volatile("" ::: "memory");
        if (kt < 30) {
            int st = cur + 2; if (st >= 3) st -= 3;   // buf read in iter kt-1
            QSTAGE((kt + 2) * 32, st * 8192);
        }
        QCOMP(cur * 4096);
        cur = (cur == 2) ? 0 : cur + 1;
    }
    asm volatile("s_waitcnt vmcnt(0)" ::: "memory");
    __builtin_amdgcn_s_barrier();
    asm volatile("" ::: "memory");
    QCOMP(cur * 4096);
#undef QSTAGE
#undef QCOMP

#pragma unroll
    for (int mt = 0; mt < 4; ++mt)
#pragma unroll
        for (int nt = 0; nt < 4; ++nt) {
            const int gm0 = m0 + wy * 64 + mt * 16 + quad * 4;
            const int bn  = n_i * 128 + wx * 64 + nt * 16 + L;
            const float bvv = bp[bn];
            const int hh = bn >> 6, dd = bn & 63;
            if (which < 2) {
#pragma unroll
                for (int r = 0; r < 4; ++r) {
                    const int gm = gm0 + r;
                    const int bb = gm >> 11, tt = gm & 2047;
                    outp[((size_t)(bb * 16 + hh) * 2048 + tt) * 64 + dd] =
                        f2bf((acc[mt][nt][r] + bvv) * qscale);
                }
            } else {
                const int bb = gm0 >> 11, t0 = gm0 & 2047;
                ushort4 pk;
                pk.x = f2bf(acc[mt][nt][0] + bvv);
                pk.y = f2bf(acc[mt][nt][1] + bvv);
                pk.z = f2bf(acc[mt][nt][2] + bvv);
                pk.w = f2bf(acc[mt][nt][3] + bvv);
                *(ushort4*)(outp + ((size_t)(bb * 16 + hh) * 64 + dd) * 2048 + t0) = pk;
            }
        }
}

// ---------------------------------------------------------------------------
// Wo GEMM. 128x64 tile, flat grid 512, XCD swizzle.
// R9: 3-buffer LDS, depth-2 prefetch, counted vmcnt(3) + raw s_barrier.
// ---------------------------------------------------------------------------
__global__ __launch_bounds__(256)
void gemm_out(const unsigned short* __restrict__ X, const unsigned short* __restrict__ W,
              const float* __restrict__ bias, float* __restrict__ outp)
{
    __shared__ unsigned short Xs[3 * 4096], Ws[3 * 2048];   // 24KB + 12KB
    const int tid = threadIdx.x;
    const int w = tid >> 6, ln = tid & 63;
    const int quad = ln >> 4, L = ln & 15;

    const int bid = blockIdx.x;
    const int xcd = bid & 7, j = bid >> 3;
    const int m0 = (xcd * 4 + (j >> 4)) * 128;
    const int n0 = (j & 15) * 64;

    // staging geometry (loop-invariant): 3 gl16 per wave per K-tile
    const int cix0 = ln, cix1 = 64 + ln;
    const int rowx0 = w * 32 + (cix0 >> 2), rowx1 = w * 32 + (cix1 >> 2);
    const int gcx0 = (cix0 & 3) ^ ((rowx0 >> 1) & 3);
    const int gcx1 = (cix1 & 3) ^ ((rowx1 >> 1) & 3);
    const int roww = w * 16 + (ln >> 2);
    const int gcw = (ln & 3) ^ ((roww >> 1) & 3);
    const size_t gxx0 = (size_t)(m0 + rowx0) * 1024 + gcx0 * 8;
    const size_t gxx1 = (size_t)(m0 + rowx1) * 1024 + gcx1 * 8;
    const size_t gww  = (size_t)(n0 + roww) * 1024 + gcw * 8;

    f32x4 acc[2][4];
#pragma unroll
    for (int i = 0; i < 2; ++i)
#pragma unroll
        for (int jj = 0; jj < 4; ++jj) { f32x4 z = {0.f,0.f,0.f,0.f}; acc[i][jj] = z; }

#define OSTAGE(k0_, bf_)                                                       \
    do {                                                                       \
        gl16(X + gxx0 + (k0_), (char*)Xs + (bf_) * 8192 + w * 2048);           \
        gl16(X + gxx1 + (k0_), (char*)Xs + (bf_) * 8192 + w * 2048 + 1024);    \
        gl16(W + gww  + (k0_), (char*)Ws + (bf_) * 4096 + w * 1024);           \
    } while (0)

#define OCOMP(bf_)                                                             \
    do {                                                                       \
        const unsigned short* Xc = Xs + (bf_) * 4096;                          \
        const unsigned short* Wc = Ws + (bf_) * 2048;                          \
        bf16x8 ah[2], bh[4];                                                   \
        _Pragma("unroll")                                                      \
        for (int mt = 0; mt < 2; ++mt) {                                       \
            const int row = w * 32 + mt * 16 + L;                              \
            ah[mt] = *(const bf16x8*)(Xc + row * 32 +                          \
                                      ((quad ^ ((row >> 1) & 3)) * 8));        \
        }                                                                      \
        _Pragma("unroll")                                                      \
        for (int nt = 0; nt < 4; ++nt) {                                       \
            const int row = nt * 16 + L;                                       \
            bh[nt] = *(const bf16x8*)(Wc + row * 32 +                          \
                                      ((quad ^ ((row >> 1) & 3)) * 8));        \
        }                                                                      \
        _Pragma("unroll")                                                      \
        for (int mt = 0; mt < 2; ++mt)                                         \
            _Pragma("unroll")                                                  \
            for (int nt = 0; nt < 4; ++nt)                                     \
                acc[mt][nt] = mfma16(ah[mt], bh[nt], acc[mt][nt]);             \
    } while (0)

    OSTAGE(0, 0);
    OSTAGE(32, 1);

    int cur = 0;
    for (int kt = 0; kt < 31; ++kt) {
        asm volatile("s_waitcnt vmcnt(3)" ::: "memory");
        __builtin_amdgcn_s_barrier();
        asm volatile("" ::: "memory");
        if (kt < 30) {
            int st = cur + 2; if (st >= 3) st -= 3;
            OSTAGE((kt + 2) * 32, st);
        }
        OCOMP(cur);
        cur = (cur == 2) ? 0 : cur + 1;
    }
    asm volatile("s_waitcnt vmcnt(0)" ::: "memory");
    __builtin_amdgcn_s_barrier();
    asm volatile("" ::: "memory");
    OCOMP(cur);
#undef OSTAGE
#undef OCOMP

#pragma unroll
    for (int mt = 0; mt < 2; ++mt)
#pragma unroll
        for (int nt = 0; nt < 4; ++nt) {
            const int gm0 = m0 + w * 32 + mt * 16 + quad * 4;
            const int gn  = n0 + nt * 16 + L;
            const float bvv = bias[gn];
#pragma unroll
            for (int r = 0; r < 4; ++r)
                outp[(size_t)(gm0 + r) * 1024 + gn] = acc[mt][nt][r] + bvv;
        }
}

// ---------------------------------------------------------------------------
// Flash R13. Grid 256, block 512 (8 waves): xcd=bid&7, j=bid>>3,
// bh=xcd*4+(j&3), qt=j>>2 (q-tile 256 rows). Wave (wq,wk): wq=w&3 owns 64 q
// rows, wk=w>>2 owns 32 keys of each 64-key tile. S^T = K Q^T, O^T = V^T P^T
// with P in registers (R12 slot-relabel: PV slot k = quad*8 + mt*4 + r).
// K/V TRIPLE-buffered, stage-after-barrier, counted vmcnt(2) (2 gl16/wave/
// tile, depth 2). setprio(1) around MFMA clusters. LDS: K 3x8KB @0, V 3x8KB
// @24576B; retired bufs reused as 64KB O-reduce region. 1 block/CU.
// ---------------------------------------------------------------------------
__global__ __launch_bounds__(512, 2)
void flash(const unsigned short* __restrict__ Qh, const unsigned short* __restrict__ Kh,
           const unsigned short* __restrict__ Vt, unsigned short* __restrict__ A)
{
    __shared__ unsigned short SM[32768];         // 64KB union: K/V bufs | O-reduce
    __shared__ float Lsc[4 * 4 * 64];            // 4KB cross-wave lacc scalars
    const int tid = threadIdx.x;
    const int w = tid >> 6, ln = tid & 63;
    const int quad = ln >> 4, L = ln & 15;
    const int wq = w & 3, wk = w >> 2;

    const int bid = blockIdx.x;
    const int xcd = bid & 7, j = bid >> 3;
    const int bh_i = xcd * 4 + (j & 3);
    const int qt = j >> 2;                       // 0..7, 256-row q tiles
    const int b = bh_i >> 4, h = bh_i & 15;

    const unsigned short* Qb = Qh + ((size_t)bh_i * 2048 + qt * 256 + wq * 64) * 64;
    const unsigned short* Kb = Kh + (size_t)bh_i * 2048 * 64;
    const unsigned short* Vb = Vt + (size_t)bh_i * 64 * 2048;

    // Q as B-operand: B[n=q=nt*16+L][k=d]
    bf16x8 bq[4][2];
#pragma unroll
    for (int nt = 0; nt < 4; ++nt)
#pragma unroll
        for (int kc = 0; kc < 2; ++kc)
            bq[nt][kc] = *(const bf16x8*)(Qb + (nt * 16 + L) * 64 + kc * 32 + quad * 8);

    const short one_bf = (short)0x3F80;
    bf16x8 bone = {one_bf, one_bf, one_bf, one_bf, one_bf, one_bf, one_bf, one_bf};

    f32x4 o[4][4];        // O^T partial: [mtd over d][nt over q]
    f32x4 lacc[4];
#pragma unroll
    for (int mtd = 0; mtd < 4; ++mtd)
#pragma unroll
        for (int nt = 0; nt < 4; ++nt) { f32x4 z = {0.f,0.f,0.f,0.f}; o[mtd][nt] = z; }
#pragma unroll
    for (int nt = 0; nt < 4; ++nt) { f32x4 z = {0.f,0.f,0.f,0.f}; lacc[nt] = z; }

    // staging: one 1KB K seg + one 1KB V seg per wave (seg = w, 8 segs/tile)
    const int ci = w * 64 + ln;
    const int rr = ci >> 3;
    const int gc = (ci & 7) ^ (rr & 7);

    // V-fragment addressing (loop-invariant). PV slot k = quad*8 + mt*4 + r
    // maps to key (within wave's 32) = mt*16 + quad*4 + r. LDS V layout has
    // granule swizzle LDS[row][g] = global[row][g ^ (row&7)] (8-key granules).
    const int rbv = L & 7;
    const int vg0 = ((wk * 4 + (quad >> 1)) ^ rbv) * 8 + (quad & 1) * 4;        // keys quad*4..+3
    const int vg1 = ((wk * 4 + 2 + (quad >> 1)) ^ rbv) * 8 + (quad & 1) * 4;    // keys 16+quad*4..+3

#define STAGE(kt_, buf_)                                                        \
    do {                                                                        \
        gl16(Kb + (size_t)((kt_) * 64 + rr) * 64 + gc * 8,                      \
             (char*)SM + (buf_) * 8192 + w * 1024);                             \
        gl16(Vb + (size_t)rr * 2048 + (kt_) * 64 + gc * 8,                      \
             (char*)SM + 24576 + (buf_) * 8192 + w * 1024);                     \
    } while (0)

    STAGE(0, 0);
    STAGE(1, 1);

    int cur = 0, st = 2;
    for (int kt = 0; kt < 32; ++kt) {
        // own 2 loads for buf[cur] done; buf[kt+1]'s 2 may stay in flight
        if (kt < 31) {
            asm volatile("s_waitcnt vmcnt(2)" ::: "memory");
        } else {
            asm volatile("s_waitcnt vmcnt(0)" ::: "memory");
        }
        __builtin_amdgcn_s_barrier();
        asm volatile("" ::: "memory");
        if (kt < 30) STAGE(kt + 2, st);        // overwrites buf computed at kt-1

        const unsigned short* Ksb = SM + cur * 4096;
        const unsigned short* Vsb = SM + 12288 + cur * 4096;

        // K as A-operand: A[m=key=wk*32+mt*16+L][k=d]
        bf16x8 ak[2][2];
#pragma unroll
        for (int mt = 0; mt < 2; ++mt)
#pragma unroll
            for (int kc = 0; kc < 2; ++kc) {
                const int row = wk * 32 + mt * 16 + L;
                ak[mt][kc] = *(const bf16x8*)(Ksb + row * 64 + (((kc * 4 + quad) ^ (L & 7)) * 8));
            }

        // S^T = K Q^T : col(n)=q=L, row(m)=key = mt*16 + quad*4 + r
        f32x4 s[2][4];
        __builtin_amdgcn_s_setprio(1);
#pragma unroll
        for (int mt = 0; mt < 2; ++mt)
#pragma unroll
            for (int nt = 0; nt < 4; ++nt) {
                f32x4 z = {0.f,0.f,0.f,0.f};
                z = mfma16(ak[mt][0], bq[nt][0], z);
                z = mfma16(ak[mt][1], bq[nt][1], z);
                s[mt][nt] = z;
            }
        __builtin_amdgcn_s_setprio(0);

        // p = exp2(s) packed straight into PV B-frags (slot k = quad*8+mt*4+r)
        bf16x8 pbx[4];
#pragma unroll
        for (int nt = 0; nt < 4; ++nt) {
            u32x4 pd;
            pd.x = pk2bf(__builtin_amdgcn_exp2f(s[0][nt][0]),
                         __builtin_amdgcn_exp2f(s[0][nt][1]));
            pd.y = pk2bf(__builtin_amdgcn_exp2f(s[0][nt][2]),
                         __builtin_amdgcn_exp2f(s[0][nt][3]));
            pd.z = pk2bf(__builtin_amdgcn_exp2f(s[1][nt][0]),
                         __builtin_amdgcn_exp2f(s[1][nt][1]));
            pd.w = pk2bf(__builtin_amdgcn_exp2f(s[1][nt][2]),
                         __builtin_amdgcn_exp2f(s[1][nt][3]));
            pbx[nt] = __builtin_bit_cast(bf16x8, pd);
        }

        // V as A-operand with matching key order: slot k=quad*8+mt*4+r holds
        // V^T[d=mtd*16+L][key = wk*32 + mt*16 + quad*4 + r]
        bf16x8 av[4];
#pragma unroll
        for (int mtd = 0; mtd < 4; ++mtd) {
            const unsigned short* Vr = Vsb + (mtd * 16 + L) * 64;
            u64x2 t;
            t.x = *(const unsigned long long*)(Vr + vg0);
            t.y = *(const unsigned long long*)(Vr + vg1);
            av[mtd] = __builtin_bit_cast(bf16x8, t);
        }

        __builtin_amdgcn_s_setprio(1);
#pragma unroll
        for (int mtd = 0; mtd < 4; ++mtd)
#pragma unroll
            for (int nt = 0; nt < 4; ++nt)
                o[mtd][nt] = mfma16(av[mtd], pbx[nt], o[mtd][nt]);
#pragma unroll
        for (int nt = 0; nt < 4; ++nt)
            lacc[nt] = mfma16(bone, pbx[nt], lacc[nt]);
        __builtin_amdgcn_s_setprio(0);

        cur = (cur == 2) ? 0 : cur + 1;
        st  = (st  == 2) ? 0 : st  + 1;
    }
#undef STAGE

    // cross-wave reduction over key-halves through retired K/V LDS (64KB)
    __syncthreads();
    float* Rb = (float*)SM;                // 16384 floats = 64 KB (4 wq x 16KB)
    if (wk == 1) {
#pragma unroll
        for (int mtd = 0; mtd < 4; ++mtd)
#pragma unroll
            for (int nt = 0; nt < 4; ++nt)
                *(f32x4*)(Rb + wq * 4096 + (mtd * 4 + nt) * 256 + ln * 4) = o[mtd][nt];
#pragma unroll
        for (int nt = 0; nt < 4; ++nt)
            Lsc[wq * 256 + nt * 64 + ln] = lacc[nt][0];
    }
    __syncthreads();
    if (wk == 0) {
#pragma unroll
        for (int mtd = 0; mtd < 4; ++mtd)
#pragma unroll
            for (int nt = 0; nt < 4; ++nt)
                o[mtd][nt] += *(const f32x4*)(Rb + wq * 4096 + (mtd * 4 + nt) * 256 + ln * 4);

        // epilogue: O^T/l -> bf16 into A [B*T, D]; lane q=nt*16+L, rows d.
#pragma unroll
        for (int nt = 0; nt < 4; ++nt) {
            const float lsum = lacc[nt][0] + Lsc[wq * 256 + nt * 64 + ln];
            const float inv = 1.0f / lsum;
            const int qrow = b * 2048 + qt * 256 + wq * 64 + nt * 16 + L;
#pragma unroll
            for (int mtd = 0; mtd < 4; ++mtd) {
                const int d0 = mtd * 16 + quad * 4;
                ushort4 pk;
                pk.x = f2bf(o[mtd][nt][0] * inv);
                pk.y = f2bf(o[mtd][nt][1] * inv);
                pk.z = f2bf(o[mtd][nt][2] * inv);
                pk.w = f2bf(o[mtd][nt][3] * inv);
                *(ushort4*)(A + (size_t)qrow * 1024 + h * 64 + d0) = pk;
            }
        }
    }
}

// ---------------------------------------------------------------------------
extern "C" void kernel_launch(void* const* d_in, const int* in_sizes, int n_in,
                              void* d_out, int out_size, void* d_ws, size_t ws_size,
                              hipStream_t stream) {
    const float* q  = (const float*)d_in[0];
    const float* k  = (const float*)d_in[1];
    const float* v  = (const float*)d_in[2];
    const float* Wq = (const float*)d_in[3];
    const float* bq = (const float*)d_in[4];
    const float* Wk = (const float*)d_in[5];
    const float* bk = (const float*)d_in[6];
    const float* Wv = (const float*)d_in[7];
    const float* bv = (const float*)d_in[8];
    const float* Wo = (const float*)d_in[9];
    const float* bo = (const float*)d_in[10];

    unsigned short* W = (unsigned short*)d_ws;
    unsigned short *Xall = W;                      // q,k,v bf16 [3*E22]
    unsigned short *Wcat = W + 3 * E22;            // [3072,1024] bf16
    unsigned short *Wob  = Wcat + 3 * E20;         // [1024,1024] bf16
    unsigned short *Qhp  = W + 4 * E22;            // [B,H,T,64] (pre-scaled)
    unsigned short *Khp  = W + 5 * E22;
    unsigned short *Vtp  = W + 6 * E22;            // [B,H,64,T]
    unsigned short *A    = W;                      // reuse q_b (dead)

    split_all<<<16384, 256, 0, stream>>>(q, k, v, Wq, Wk, Wv, Wo, W);

    gemm_qkv<<<768, 256, 0, stream>>>(Xall, Wcat, bq, bk, bv, Qhp, Khp, Vtp);

    flash<<<256, 512, 0, stream>>>(Qhp, Khp, Vtp, A);

    gemm_out<<<512, 256, 0, stream>>>(A, Wob, bo, (float*)d_out);
}

// Round 6
// 211.661 us; speedup vs baseline: 1.0348x; 1.0348x over previous
//
#include <hip/hip_runtime.h>

// MultiHeadAttention B=2,T=2048,D=1024,H=16,hd=64 fp32.
// R14: flash = R12 geometry (grid 512, 4-wave blocks, 2 blocks/CU, q-tile
// 128, P-in-registers PV via slot-relabel) + ONE change: K/V triple-buffered
// with stage-after-barrier and counted s_waitcnt vmcnt(4) (4 gl16/wave/tile,
// depth 2) instead of __syncthreads' vmcnt(0) drain. setprio(1) around MFMA
// clusters. R13's 512-thread single-block geometry reverted (barrier-locking
// all CU waves cost more than amortization saved; FETCH unchanged proved the
// L2-traffic saving was not the bottleneck). gemm_qkv/gemm_out/split
// unchanged from R9.

typedef __attribute__((ext_vector_type(8))) short bf16x8;
typedef __attribute__((ext_vector_type(4))) float f32x4;
typedef __attribute__((ext_vector_type(4))) unsigned int u32x4;
typedef __attribute__((ext_vector_type(2))) unsigned long long u64x2;

#define E22 ((size_t)1 << 22)
#define E20 ((size_t)1 << 20)

__device__ __forceinline__ unsigned short f2bf(float x) {
    unsigned int u = __float_as_uint(x);
    u += 0x7fffu + ((u >> 16) & 1u);
    return (unsigned short)(u >> 16);
}
__device__ __forceinline__ unsigned int pk2bf(float a, float b) {
    // [b_hi16 | a_hi16] in one v_perm_b32
    return __builtin_amdgcn_perm(__float_as_uint(a), __float_as_uint(b), 0x03020706u);
}
__device__ __forceinline__ void gl16(const void* g, void* l) {
    __builtin_amdgcn_global_load_lds(
        (const __attribute__((address_space(1))) void*)g,
        (__attribute__((address_space(3))) void*)l, 16, 0, 0);
}
__device__ __forceinline__ f32x4 mfma16(bf16x8 a, bf16x8 b, f32x4 c) {
    return __builtin_amdgcn_mfma_f32_16x16x32_bf16(a, b, c, 0, 0, 0);
}

// ---------------------------------------------------------------------------
// split: fp32 -> bf16. q/k/v -> [0,3*E22); Wq,Wk,Wv -> Wcat[3072,1024] at
// 3*E22; Wo -> 3*E22+3*E20. 4M threads, one float4 each.
// ---------------------------------------------------------------------------
__global__ __launch_bounds__(256)
void split_all(const float* __restrict__ q, const float* __restrict__ k,
               const float* __restrict__ v, const float* __restrict__ wq,
               const float* __restrict__ wk, const float* __restrict__ wv,
               const float* __restrict__ wo, unsigned short* __restrict__ ws)
{
    const size_t t = (size_t)blockIdx.x * 256 + threadIdx.x;
    const size_t e = t * 4;
    const float* src; unsigned short* dst; size_t off;
    if (e < 3 * E22) {
        const unsigned int which = (unsigned int)(e >> 22);
        src = which == 0 ? q : (which == 1 ? k : v);
        off = e & (E22 - 1);
        dst = ws + (size_t)which * E22;
    } else {
        const size_t e2 = e - 3 * E22;
        const unsigned int which = (unsigned int)(e2 >> 20);
        off = e2 & (E20 - 1);
        src = which == 0 ? wq : (which == 1 ? wk : (which == 2 ? wv : wo));
        dst = ws + 3 * E22 + (size_t)which * E20;
    }
    const float4 xv = *(const float4*)(src + off);
    ushort4 h4;
    h4.x = f2bf(xv.x); h4.y = f2bf(xv.y); h4.z = f2bf(xv.z); h4.w = f2bf(xv.w);
    *(ushort4*)(dst + off) = h4;
}

// ---------------------------------------------------------------------------
// Fused QKV bf16 GEMM. Flat grid 768, XCD swizzle. Q output (which==0) is
// PRE-SCALED by log2e/8 so flash's softmax is a bare exp2.
// R9: 3-buffer LDS, depth-2 prefetch, counted vmcnt(4) + raw s_barrier.
// ---------------------------------------------------------------------------
__global__ __launch_bounds__(256)
void gemm_qkv(const unsigned short* __restrict__ Xall,
              const unsigned short* __restrict__ Wcat,
              const float* __restrict__ bq, const float* __restrict__ bk,
              const float* __restrict__ bv, unsigned short* __restrict__ Qhp,
              unsigned short* __restrict__ Khp, unsigned short* __restrict__ Vtp)
{
    __shared__ unsigned short Xs[3 * 4096], Ws[3 * 4096];   // 3 bufs x 8KB each
    const int tid = threadIdx.x;
    const int w = tid >> 6, ln = tid & 63;
    const int quad = ln >> 4, L = ln & 15;
    const int wy = w >> 1, wx = w & 1;

    const int bid = blockIdx.x;
    const int xcd = bid & 7, j = bid >> 3;
    const int gg = xcd * 12 + (j >> 3);
    const int which = gg >> 5, m_i = gg & 31, n_i = j & 7;
    const int m0 = m_i * 128;

    const unsigned short* X = Xall + (size_t)which * E22;
    const unsigned short* W = Wcat + ((size_t)which * 1024 + n_i * 128) * 1024;
    const float* bp = which == 0 ? bq : (which == 1 ? bk : bv);
    unsigned short* outp = which == 0 ? Qhp : (which == 1 ? Khp : Vtp);
    const float qscale = which == 0 ? 0.18033688011f : 1.0f;   // log2(e)/8

    // staging geometry (loop-invariant): 4 gl16 per wave per K-tile
    const int ci0 = ln, ci1 = 64 + ln;
    const int row0 = w * 32 + (ci0 >> 2), row1 = w * 32 + (ci1 >> 2);
    const int gc0 = (ci0 & 3) ^ ((row0 >> 1) & 3);
    const int gc1 = (ci1 & 3) ^ ((row1 >> 1) & 3);
    const int lb0 = w * 2048, lb1 = w * 2048 + 1024;          // byte offsets
    const unsigned short* Xbp = X + (size_t)m0 * 1024;
    const size_t gx0 = (size_t)row0 * 1024 + gc0 * 8;
    const size_t gx1 = (size_t)row1 * 1024 + gc1 * 8;

    f32x4 acc[4][4];
#pragma unroll
    for (int i = 0; i < 4; ++i)
#pragma unroll
        for (int jj = 0; jj < 4; ++jj) { f32x4 z = {0.f,0.f,0.f,0.f}; acc[i][jj] = z; }

#define QSTAGE(k0_, bo_)                                                       \
    do {                                                                       \
        gl16(Xbp + gx0 + (k0_), (char*)Xs + (bo_) + lb0);                      \
        gl16(W   + gx0 + (k0_), (char*)Ws + (bo_) + lb0);                      \
        gl16(Xbp + gx1 + (k0_), (char*)Xs + (bo_) + lb1);                      \
        gl16(W   + gx1 + (k0_), (char*)Ws + (bo_) + lb1);                      \
    } while (0)

#define QCOMP(eo_)                                                             \
    do {                                                                       \
        const unsigned short* Xc = Xs + (eo_);                                 \
        const unsigned short* Wc = Ws + (eo_);                                 \
        bf16x8 ah[4], bh[4];                                                   \
        _Pragma("unroll")                                                      \
        for (int mt = 0; mt < 4; ++mt) {                                       \
            const int row = wy * 64 + mt * 16 + L;                             \
            ah[mt] = *(const bf16x8*)(Xc + row * 32 +                          \
                                      ((quad ^ ((row >> 1) & 3)) * 8));        \
        }                                                                      \
        _Pragma("unroll")                                                      \
        for (int nt = 0; nt < 4; ++nt) {                                       \
            const int row = wx * 64 + nt * 16 + L;                             \
            bh[nt] = *(const bf16x8*)(Wc + row * 32 +                          \
                                      ((quad ^ ((row >> 1) & 3)) * 8));        \
        }                                                                      \
        _Pragma("unroll")                                                      \
        for (int mt = 0; mt < 4; ++mt)                                         \
            _Pragma("unroll")                                                  \
            for (int nt = 0; nt < 4; ++nt)                                     \
                acc[mt][nt] = mfma16(ah[mt], bh[nt], acc[mt][nt]);             \
    } while (0)

    QSTAGE(0, 0);
    QSTAGE(32, 8192);

    int cur = 0;
    for (int kt = 0; kt < 31; ++kt) {
        // own 4 loads for buf[cur] done; next tile's 4 may stay in flight
        asm volatile("s_waitcnt vmcnt(4)" ::: "memory");
        __builtin_amdgcn_s_barrier();
        asm volatile("" ::: "memory");
        if (kt < 30) {
            int st = cur + 2; if (st >= 3) st -= 3;   // buf read in iter kt-1
            QSTAGE((kt + 2) * 32, st * 8192);
        }
        QCOMP(cur * 4096);
        cur = (cur == 2) ? 0 : cur + 1;
    }
    asm volatile("s_waitcnt vmcnt(0)" ::: "memory");
    __builtin_amdgcn_s_barrier();
    asm volatile("" ::: "memory");
    QCOMP(cur * 4096);
#undef QSTAGE
#undef QCOMP

#pragma unroll
    for (int mt = 0; mt < 4; ++mt)
#pragma unroll
        for (int nt = 0; nt < 4; ++nt) {
            const int gm0 = m0 + wy * 64 + mt * 16 + quad * 4;
            const int bn  = n_i * 128 + wx * 64 + nt * 16 + L;
            const float bvv = bp[bn];
            const int hh = bn >> 6, dd = bn & 63;
            if (which < 2) {
#pragma unroll
                for (int r = 0; r < 4; ++r) {
                    const int gm = gm0 + r;
                    const int bb = gm >> 11, tt = gm & 2047;
                    outp[((size_t)(bb * 16 + hh) * 2048 + tt) * 64 + dd] =
                        f2bf((acc[mt][nt][r] + bvv) * qscale);
                }
            } else {
                const int bb = gm0 >> 11, t0 = gm0 & 2047;
                ushort4 pk;
                pk.x = f2bf(acc[mt][nt][0] + bvv);
                pk.y = f2bf(acc[mt][nt][1] + bvv);
                pk.z = f2bf(acc[mt][nt][2] + bvv);
                pk.w = f2bf(acc[mt][nt][3] + bvv);
                *(ushort4*)(outp + ((size_t)(bb * 16 + hh) * 64 + dd) * 2048 + t0) = pk;
            }
        }
}

// ---------------------------------------------------------------------------
// Wo GEMM. 128x64 tile, flat grid 512, XCD swizzle.
// R9: 3-buffer LDS, depth-2 prefetch, counted vmcnt(3) + raw s_barrier.
// ---------------------------------------------------------------------------
__global__ __launch_bounds__(256)
void gemm_out(const unsigned short* __restrict__ X, const unsigned short* __restrict__ W,
              const float* __restrict__ bias, float* __restrict__ outp)
{
    __shared__ unsigned short Xs[3 * 4096], Ws[3 * 2048];   // 24KB + 12KB
    const int tid = threadIdx.x;
    const int w = tid >> 6, ln = tid & 63;
    const int quad = ln >> 4, L = ln & 15;

    const int bid = blockIdx.x;
    const int xcd = bid & 7, j = bid >> 3;
    const int m0 = (xcd * 4 + (j >> 4)) * 128;
    const int n0 = (j & 15) * 64;

    // staging geometry (loop-invariant): 3 gl16 per wave per K-tile
    const int cix0 = ln, cix1 = 64 + ln;
    const int rowx0 = w * 32 + (cix0 >> 2), rowx1 = w * 32 + (cix1 >> 2);
    const int gcx0 = (cix0 & 3) ^ ((rowx0 >> 1) & 3);
    const int gcx1 = (cix1 & 3) ^ ((rowx1 >> 1) & 3);
    const int roww = w * 16 + (ln >> 2);
    const int gcw = (ln & 3) ^ ((roww >> 1) & 3);
    const size_t gxx0 = (size_t)(m0 + rowx0) * 1024 + gcx0 * 8;
    const size_t gxx1 = (size_t)(m0 + rowx1) * 1024 + gcx1 * 8;
    const size_t gww  = (size_t)(n0 + roww) * 1024 + gcw * 8;

    f32x4 acc[2][4];
#pragma unroll
    for (int i = 0; i < 2; ++i)
#pragma unroll
        for (int jj = 0; jj < 4; ++jj) { f32x4 z = {0.f,0.f,0.f,0.f}; acc[i][jj] = z; }

#define OSTAGE(k0_, bf_)                                                       \
    do {                                                                       \
        gl16(X + gxx0 + (k0_), (char*)Xs + (bf_) * 8192 + w * 2048);           \
        gl16(X + gxx1 + (k0_), (char*)Xs + (bf_) * 8192 + w * 2048 + 1024);    \
        gl16(W + gww  + (k0_), (char*)Ws + (bf_) * 4096 + w * 1024);           \
    } while (0)

#define OCOMP(bf_)                                                             \
    do {                                                                       \
        const unsigned short* Xc = Xs + (bf_) * 4096;                          \
        const unsigned short* Wc = Ws + (bf_) * 2048;                          \
        bf16x8 ah[2], bh[4];                                                   \
        _Pragma("unroll")                                                      \
        for (int mt = 0; mt < 2; ++mt) {                                       \
            const int row = w * 32 + mt * 16 + L;                              \
            ah[mt] = *(const bf16x8*)(Xc + row * 32 +                          \
                                      ((quad ^ ((row >> 1) & 3)) * 8));        \
        }                                                                      \
        _Pragma("unroll")                                                      \
        for (int nt = 0; nt < 4; ++nt) {                                       \
            const int row = nt * 16 + L;                                       \
            bh[nt] = *(const bf16x8*)(Wc + row * 32 +                          \
                                      ((quad ^ ((row >> 1) & 3)) * 8));        \
        }                                                                      \
        _Pragma("unroll")                                                      \
        for (int mt = 0; mt < 2; ++mt)                                         \
            _Pragma("unroll")                                                  \
            for (int nt = 0; nt < 4; ++nt)                                     \
                acc[mt][nt] = mfma16(ah[mt], bh[nt], acc[mt][nt]);             \
    } while (0)

    OSTAGE(0, 0);
    OSTAGE(32, 1);

    int cur = 0;
    for (int kt = 0; kt < 31; ++kt) {
        asm volatile("s_waitcnt vmcnt(3)" ::: "memory");
        __builtin_amdgcn_s_barrier();
        asm volatile("" ::: "memory");
        if (kt < 30) {
            int st = cur + 2; if (st >= 3) st -= 3;
            OSTAGE((kt + 2) * 32, st);
        }
        OCOMP(cur);
        cur = (cur == 2) ? 0 : cur + 1;
    }
    asm volatile("s_waitcnt vmcnt(0)" ::: "memory");
    __builtin_amdgcn_s_barrier();
    asm volatile("" ::: "memory");
    OCOMP(cur);
#undef OSTAGE
#undef OCOMP

#pragma unroll
    for (int mt = 0; mt < 2; ++mt)
#pragma unroll
        for (int nt = 0; nt < 4; ++nt) {
            const int gm0 = m0 + w * 32 + mt * 16 + quad * 4;
            const int gn  = n0 + nt * 16 + L;
            const float bvv = bias[gn];
#pragma unroll
            for (int r = 0; r < 4; ++r)
                outp[(size_t)(gm0 + r) * 1024 + gn] = acc[mt][nt][r] + bvv;
        }
}

// ---------------------------------------------------------------------------
// Flash R14. Flat grid 512 (256 thr): xcd=bid&7, j=bid>>3, bh=xcd*4+(j&3),
// qt=j>>2 (q-tile 128). Wave (wq,wk) owns q-half wq (64 rows) x key-half wk
// (32 keys of each 64-key tile). S^T = K Q^T, O^T = V^T P^T with P in
// registers (slot relabel: PV slot k = quad*8 + mt*4 + r; V read with the
// matching permuted key order, 2x ds_read_b64/frag).
// K/V TRIPLE-buffered, stage-after-barrier, counted vmcnt(4) (4 gl16/wave/
// tile, depth 2); vmcnt(0) only on the last tile. setprio(1) around MFMA.
// LDS: K 3x8KB @0, V 3x8KB @24KB; retired bufs reused as 32KB O-reduce.
// 50KB total -> 2 blocks/CU.
// ---------------------------------------------------------------------------
__global__ __launch_bounds__(256, 2)
void flash(const unsigned short* __restrict__ Qh, const unsigned short* __restrict__ Kh,
           const unsigned short* __restrict__ Vt, unsigned short* __restrict__ A)
{
    __shared__ unsigned short SM[24576];         // 48KB: K bufs [0,24KB), V bufs [24,48KB)
    __shared__ float Lsc[2 * 4 * 64];            // 2KB cross-wave lacc scalars
    const int tid = threadIdx.x;
    const int w = tid >> 6, ln = tid & 63;
    const int quad = ln >> 4, L = ln & 15;
    const int wq = w & 1, wk = w >> 1;

    const int bid = blockIdx.x;
    const int xcd = bid & 7, j = bid >> 3;
    const int bh_i = xcd * 4 + (j & 3);
    const int qt = j >> 2;                       // 0..15, 128-row q tiles
    const int b = bh_i >> 4, h = bh_i & 15;

    const unsigned short* Qb = Qh + ((size_t)bh_i * 2048 + qt * 128 + wq * 64) * 64;
    const unsigned short* Kb = Kh + (size_t)bh_i * 2048 * 64;
    const unsigned short* Vb = Vt + (size_t)bh_i * 64 * 2048;

    // Q as B-operand: B[n=q=nt*16+L][k=d]
    bf16x8 bq[4][2];
#pragma unroll
    for (int nt = 0; nt < 4; ++nt)
#pragma unroll
        for (int kc = 0; kc < 2; ++kc)
            bq[nt][kc] = *(const bf16x8*)(Qb + (nt * 16 + L) * 64 + kc * 32 + quad * 8);

    const short one_bf = (short)0x3F80;
    bf16x8 bone = {one_bf, one_bf, one_bf, one_bf, one_bf, one_bf, one_bf, one_bf};

    f32x4 o[4][4];        // O^T partial: [mtd over d][nt over q]
    f32x4 lacc[4];
#pragma unroll
    for (int mtd = 0; mtd < 4; ++mtd)
#pragma unroll
        for (int nt = 0; nt < 4; ++nt) { f32x4 z = {0.f,0.f,0.f,0.f}; o[mtd][nt] = z; }
#pragma unroll
    for (int nt = 0; nt < 4; ++nt) { f32x4 z = {0.f,0.f,0.f,0.f}; lacc[nt] = z; }

    // staging: seg = w*2+i over 8 segs of 1KB per tile; 4 gl16/wave/tile
    const int ci0 = (w * 2 + 0) * 64 + ln, ci1 = (w * 2 + 1) * 64 + ln;
    const int rr0 = ci0 >> 3, rr1 = ci1 >> 3;
    const int gc0 = (ci0 & 7) ^ (rr0 & 7), gc1 = (ci1 & 7) ^ (rr1 & 7);

    // V-fragment addressing (loop-invariant). PV slot k = quad*8 + mt*4 + r
    // maps to key (within wave's 32) = mt*16 + quad*4 + r. LDS V layout has
    // granule swizzle LDS[row][g] = global[row][g ^ (row&7)] (8-key granules).
    const int rbv = L & 7;
    const int vg0 = ((wk * 4 + (quad >> 1)) ^ rbv) * 8 + (quad & 1) * 4;        // keys quad*4..+3
    const int vg1 = ((wk * 4 + 2 + (quad >> 1)) ^ rbv) * 8 + (quad & 1) * 4;    // keys 16+quad*4..+3

#define STAGE(kt_, buf_)                                                        \
    do {                                                                        \
        gl16(Kb + (size_t)((kt_) * 64 + rr0) * 64 + gc0 * 8,                    \
             (char*)SM + (buf_) * 8192 + (w * 2 + 0) * 1024);                   \
        gl16(Kb + (size_t)((kt_) * 64 + rr1) * 64 + gc1 * 8,                    \
             (char*)SM + (buf_) * 8192 + (w * 2 + 1) * 1024);                   \
        gl16(Vb + (size_t)rr0 * 2048 + (kt_) * 64 + gc0 * 8,                    \
             (char*)SM + 24576 + (buf_) * 8192 + (w * 2 + 0) * 1024);           \
        gl16(Vb + (size_t)rr1 * 2048 + (kt_) * 64 + gc1 * 8,                    \
             (char*)SM + 24576 + (buf_) * 8192 + (w * 2 + 1) * 1024);           \
    } while (0)

    STAGE(0, 0);
    STAGE(1, 1);

    int cur = 0, st = 2;
    for (int kt = 0; kt < 32; ++kt) {
        // own 4 loads for buf[cur] done; tile kt+1's 4 may stay in flight
        if (kt < 31) {
            asm volatile("s_waitcnt vmcnt(4)" ::: "memory");
        } else {
            asm volatile("s_waitcnt vmcnt(0)" ::: "memory");
        }
        __builtin_amdgcn_s_barrier();
        asm volatile("" ::: "memory");
        if (kt < 30) STAGE(kt + 2, st);        // overwrites buf computed at kt-1

        const unsigned short* Ksb = SM + cur * 4096;
        const unsigned short* Vsb = SM + 12288 + cur * 4096;

        // K as A-operand: A[m=key=wk*32+mt*16+L][k=d]
        bf16x8 ak[2][2];
#pragma unroll
        for (int mt = 0; mt < 2; ++mt)
#pragma unroll
            for (int kc = 0; kc < 2; ++kc) {
                const int row = wk * 32 + mt * 16 + L;
                ak[mt][kc] = *(const bf16x8*)(Ksb + row * 64 + (((kc * 4 + quad) ^ (L & 7)) * 8));
            }

        // S^T = K Q^T : col(n)=q=L, row(m)=key = mt*16 + quad*4 + r
        f32x4 s[2][4];
        __builtin_amdgcn_s_setprio(1);
#pragma unroll
        for (int mt = 0; mt < 2; ++mt)
#pragma unroll
            for (int nt = 0; nt < 4; ++nt) {
                f32x4 z = {0.f,0.f,0.f,0.f};
                z = mfma16(ak[mt][0], bq[nt][0], z);
                z = mfma16(ak[mt][1], bq[nt][1], z);
                s[mt][nt] = z;
            }
        __builtin_amdgcn_s_setprio(0);

        // p = exp2(s) packed straight into PV B-frags (slot k = quad*8+mt*4+r)
        bf16x8 pbx[4];
#pragma unroll
        for (int nt = 0; nt < 4; ++nt) {
            u32x4 pd;
            pd.x = pk2bf(__builtin_amdgcn_exp2f(s[0][nt][0]),
                         __builtin_amdgcn_exp2f(s[0][nt][1]));
            pd.y = pk2bf(__builtin_amdgcn_exp2f(s[0][nt][2]),
                         __builtin_amdgcn_exp2f(s[0][nt][3]));
            pd.z = pk2bf(__builtin_amdgcn_exp2f(s[1][nt][0]),
                         __builtin_amdgcn_exp2f(s[1][nt][1]));
            pd.w = pk2bf(__builtin_amdgcn_exp2f(s[1][nt][2]),
                         __builtin_amdgcn_exp2f(s[1][nt][3]));
            pbx[nt] = __builtin_bit_cast(bf16x8, pd);
        }

        // V as A-operand with matching key order: slot k=quad*8+mt*4+r holds
        // V^T[d=mtd*16+L][key = wk*32 + mt*16 + quad*4 + r]
        bf16x8 av[4];
#pragma unroll
        for (int mtd = 0; mtd < 4; ++mtd) {
            const unsigned short* Vr = Vsb + (mtd * 16 + L) * 64;
            u64x2 t;
            t.x = *(const unsigned long long*)(Vr + vg0);
            t.y = *(const unsigned long long*)(Vr + vg1);
            av[mtd] = __builtin_bit_cast(bf16x8, t);
        }

        __builtin_amdgcn_s_setprio(1);
#pragma unroll
        for (int mtd = 0; mtd < 4; ++mtd)
#pragma unroll
            for (int nt = 0; nt < 4; ++nt)
                o[mtd][nt] = mfma16(av[mtd], pbx[nt], o[mtd][nt]);
#pragma unroll
        for (int nt = 0; nt < 4; ++nt)
            lacc[nt] = mfma16(bone, pbx[nt], lacc[nt]);
        __builtin_amdgcn_s_setprio(0);

        cur = (cur == 2) ? 0 : cur + 1;
        st  = (st  == 2) ? 0 : st  + 1;
    }
#undef STAGE

    // cross-wave reduction over key-halves through retired K/V LDS
    __syncthreads();
    float* Rb = (float*)SM;               // 8192 floats = 32 KB
    if (wk == 1) {
#pragma unroll
        for (int mtd = 0; mtd < 4; ++mtd)
#pragma unroll
            for (int nt = 0; nt < 4; ++nt)
                *(f32x4*)(Rb + wq * 4096 + (mtd * 4 + nt) * 256 + ln * 4) = o[mtd][nt];
#pragma unroll
        for (int nt = 0; nt < 4; ++nt)
            Lsc[wq * 256 + nt * 64 + ln] = lacc[nt][0];
    }
    __syncthreads();
    if (wk == 0) {
#pragma unroll
        for (int mtd = 0; mtd < 4; ++mtd)
#pragma unroll
            for (int nt = 0; nt < 4; ++nt)
                o[mtd][nt] += *(const f32x4*)(Rb + wq * 4096 + (mtd * 4 + nt) * 256 + ln * 4);

        // epilogue: O^T/l -> bf16 into A [B*T, D]; lane q=nt*16+L, rows d.
#pragma unroll
        for (int nt = 0; nt < 4; ++nt) {
            const float lsum = lacc[nt][0] + Lsc[wq * 256 + nt * 64 + ln];
            const float inv = 1.0f / lsum;
            const int qrow = b * 2048 + qt * 128 + wq * 64 + nt * 16 + L;
#pragma unroll
            for (int mtd = 0; mtd < 4; ++mtd) {
                const int d0 = mtd * 16 + quad * 4;
                ushort4 pk;
                pk.x = f2bf(o[mtd][nt][0] * inv);
                pk.y = f2bf(o[mtd][nt][1] * inv);
                pk.z = f2bf(o[mtd][nt][2] * inv);
                pk.w = f2bf(o[mtd][nt][3] * inv);
                *(ushort4*)(A + (size_t)qrow * 1024 + h * 64 + d0) = pk;
            }
        }
    }
}

// ---------------------------------------------------------------------------
extern "C" void kernel_launch(void* const* d_in, const int* in_sizes, int n_in,
                              void* d_out, int out_size, void* d_ws, size_t ws_size,
                              hipStream_t stream) {
    const float* q  = (const float*)d_in[0];
    const float* k  = (const float*)d_in[1];
    const float* v  = (const float*)d_in[2];
    const float* Wq = (const float*)d_in[3];
    const float* bq = (const float*)d_in[4];
    const float* Wk = (const float*)d_in[5];
    const float* bk = (const float*)d_in[6];
    const float* Wv = (const float*)d_in[7];
    const float* bv = (const float*)d_in[8];
    const float* Wo = (const float*)d_in[9];
    const float* bo = (const float*)d_in[10];

    unsigned short* W = (unsigned short*)d_ws;
    unsigned short *Xall = W;                      // q,k,v bf16 [3*E22]
    unsigned short *Wcat = W + 3 * E22;            // [3072,1024] bf16
    unsigned short *Wob  = Wcat + 3 * E20;         // [1024,1024] bf16
    unsigned short *Qhp  = W + 4 * E22;            // [B,H,T,64] (pre-scaled)
    unsigned short *Khp  = W + 5 * E22;
    unsigned short *Vtp  = W + 6 * E22;            // [B,H,64,T]
    unsigned short *A    = W;                      // reuse q_b (dead)

    split_all<<<16384, 256, 0, stream>>>(q, k, v, Wq, Wk, Wv, Wo, W);

    gemm_qkv<<<768, 256, 0, stream>>>(Xall, Wcat, bq, bk, bv, Qhp, Khp, Vtp);

    flash<<<512, 256, 0, stream>>>(Qhp, Khp, Vtp, A);

    gemm_out<<<512, 256, 0, stream>>>(A, Wob, bo, (float*)d_out);
}